// Round 16
// baseline (496.145 us; speedup 1.0000x reference)
//
#include <hip/hip_runtime.h>
#include <hip/hip_bf16.h>
#include <math.h>

#define S 2048
#define D 1024
#define NH 16
#define NKV 4
#define HD 64
#define QKV_N 1536          // (NH + 2*NKV) * HD
#define NE 8
#define NI 1024
#define EPS 1e-6f

typedef __bf16 bf16_t;
typedef __bf16 __attribute__((may_alias)) abf16;
typedef __attribute__((ext_vector_type(8))) __bf16 bf16x8;
typedef __attribute__((ext_vector_type(4))) float f32x4;
union I4B8 { int4 i; bf16x8 v; bf16_t e[8]; };

// async global->LDS, 16B per lane. LDS dest must be wave-uniform base
// (HW adds lane*16); global src is per-lane.
__device__ __forceinline__ void gll16(const void* g, void* l) {
  __builtin_amdgcn_global_load_lds(
      (const __attribute__((address_space(1))) void*)g,
      (__attribute__((address_space(3))) void*)l, 16, 0, 0);
}

// NOTE (R9): XCD block swizzle REGRESSED 2x (sparse expert grids -> 2/8 XCDs). Don't re-add.
// NOTE (R12): transpose LDS bank conflicts were NOT the limiter (fixed, dur unchanged).
// NOTE (R13): 256-k transpose tiles REGRESSED (occupancy/MLP loss). R12's 64x64 pattern
//             is the accepted floor for the transpose.
// NOTE (R14): gu BN=128 REGRESSED (1 block/CU). Occupancy-for-intensity trades lost 3x.
// NOTE (R16): attn_merge fused into attn via last-block-per-qt (16 atomics/counter —
//             NOT the R4 single-line convoy). Router fan-in (2048/line) deliberately
//             NOT fused.

// ---------------------------- rmsnorm + router logits/top2 fused (MoE pre-pass)
__global__ void rmsnorm_router_kernel(const float* __restrict__ in, const float* __restrict__ w,
                                      const float* __restrict__ rw,
                                      __hip_bfloat16* __restrict__ out16,
                                      int* __restrict__ topk_e, float* __restrict__ topk_w) {
  int t = blockIdx.x;
  int tid = threadIdx.x;
  const float* row = in + (size_t)t * D;
  float v[4];
  float ss = 0.f;
#pragma unroll
  for (int i = 0; i < 4; ++i) {
    v[i] = row[tid + i * 256];
    ss += v[i] * v[i];
  }
#pragma unroll
  for (int off = 32; off; off >>= 1) ss += __shfl_xor(ss, off);
  __shared__ float wsum[4];
  __shared__ float pl[4][NE];
  int wave = tid >> 6, lane = tid & 63;
  if (lane == 0) wsum[wave] = ss;
  __syncthreads();
  float tot = wsum[0] + wsum[1] + wsum[2] + wsum[3];
  float r = rsqrtf(tot / (float)D + EPS);
  float p[NE] = {};
#pragma unroll
  for (int i = 0; i < 4; ++i) {
    int d = tid + i * 256;
    float val = v[i] * r * w[d];
    out16[(size_t)t * D + d] = __float2bfloat16(val);
    const float* rwd = rw + (size_t)d * NE;
#pragma unroll
    for (int e = 0; e < NE; ++e) p[e] += val * rwd[e];
  }
#pragma unroll
  for (int off = 32; off; off >>= 1)
#pragma unroll
    for (int e = 0; e < NE; ++e) p[e] += __shfl_xor(p[e], off);
  if (lane == 0)
#pragma unroll
    for (int e = 0; e < NE; ++e) pl[wave][e] = p[e];
  __syncthreads();
  if (tid == 0) {
    float q[NE];
#pragma unroll
    for (int e = 0; e < NE; ++e) q[e] = pl[0][e] + pl[1][e] + pl[2][e] + pl[3][e];
    float mx = q[0];
#pragma unroll
    for (int e = 1; e < NE; ++e) mx = fmaxf(mx, q[e]);
    float ex[NE];
#pragma unroll
    for (int e = 0; e < NE; ++e) ex[e] = __expf(q[e] - mx);
    int e0 = 0;
#pragma unroll
    for (int e = 1; e < NE; ++e) if (ex[e] > ex[e0]) e0 = e;
    int e1 = (e0 == 0) ? 1 : 0;
#pragma unroll
    for (int e = 0; e < NE; ++e) if (e != e0 && ex[e] > ex[e1]) e1 = e;
    float w0 = ex[e0] / (ex[e0] + ex[e1]);
    float w1 = ex[e1] / (ex[e0] + ex[e1]);
    topk_e[2 * t] = e0;  topk_e[2 * t + 1] = e1;
    topk_w[2 * t] = w0;  topk_w[2 * t + 1] = w1;
  }
}

// ------------------------------------------- ALL weight transposes + rmsnorm, ONE launch
// z<29: 64x64 tiles, register-transposed 4x4 sub-blocks (R12-verified floor).
// z==29: pre-attention rmsnorm (6 tokens per block over the 24x16 grid); block (0,0)
//        also resets the attn per-qt merge counters (runs first on stream).
__global__ void transpose_all_kernel(
    const float* __restrict__ w_qkv, const float* __restrict__ w_o,
    const float* __restrict__ w_gate, const float* __restrict__ w_up,
    const float* __restrict__ w_down, const float* __restrict__ ws_gate,
    const float* __restrict__ ws_up, const float* __restrict__ ws_down,
    __hip_bfloat16* wqkvT, __hip_bfloat16* woT, __hip_bfloat16* wgT,
    __hip_bfloat16* wuT, __hip_bfloat16* wdT, __hip_bfloat16* wsgT,
    __hip_bfloat16* wsuT, __hip_bfloat16* wsdT,
    const float* __restrict__ hidden, const float* __restrict__ in_ln,
    __hip_bfloat16* __restrict__ hb_out, int* __restrict__ qt_ctr) {
  int z = blockIdx.z;
  int tid = threadIdx.x;
  if (z == 29) {                     // fused rmsnorm (pre-attention)
    if (blockIdx.x == 0 && blockIdx.y == 0 && tid < 128) qt_ctr[tid] = 0;
    __shared__ float wsum[4];
    int base = ((int)blockIdx.y * 24 + (int)blockIdx.x) * 6;
    int wave = tid >> 6;
#pragma unroll
    for (int jj = 0; jj < 6; ++jj) {
      int t = base + jj;
      if (t < S) {
        const float* row = hidden + (size_t)t * D;
        float v[4];
        float ss = 0.f;
#pragma unroll
        for (int i = 0; i < 4; ++i) {
          v[i] = row[tid + i * 256];
          ss += v[i] * v[i];
        }
#pragma unroll
        for (int off = 32; off; off >>= 1) ss += __shfl_xor(ss, off);
        if ((tid & 63) == 0) wsum[wave] = ss;
        __syncthreads();
        float tot = wsum[0] + wsum[1] + wsum[2] + wsum[3];
        float r = rsqrtf(tot / (float)D + EPS);
#pragma unroll
        for (int i = 0; i < 4; ++i) {
          int d = tid + i * 256;
          hb_out[(size_t)t * D + d] = __float2bfloat16(v[i] * r * in_ln[d]);
        }
      }
      __syncthreads();               // wsum reuse across tokens
    }
    return;
  }
  __shared__ bf16_t tileb[64 * 66];  // [n][k], stride 66 bf16 (2-way-free banks)
  const float* W; __hip_bfloat16* WT; int Kd, Nd;
  if (z == 0)       { W = w_qkv;  WT = wqkvT; Kd = D;  Nd = QKV_N; }
  else if (z == 1)  { W = w_o;    WT = woT;   Kd = D;  Nd = D; }
  else if (z < 10)  { int e = z - 2;  W = w_gate + (size_t)e * D * NI; WT = wgT + (size_t)e * D * NI; Kd = D;  Nd = NI; }
  else if (z < 18)  { int e = z - 10; W = w_up   + (size_t)e * D * NI; WT = wuT + (size_t)e * D * NI; Kd = D;  Nd = NI; }
  else if (z < 26)  { int e = z - 18; W = w_down + (size_t)e * NI * D; WT = wdT + (size_t)e * NI * D; Kd = NI; Nd = D; }
  else if (z == 26) { W = ws_gate; WT = wsgT; Kd = D;  Nd = NI; }
  else if (z == 27) { W = ws_up;   WT = wsuT; Kd = D;  Nd = NI; }
  else              { W = ws_down; WT = wsdT; Kd = NI; Nd = D; }
  int n0 = blockIdx.x * 64, k0 = blockIdx.y * 64;
  if (n0 >= Nd || k0 >= Kd) return;
  int nq = tid & 15;                 // n sub-quad (n = nq*4 .. +3)
  int kq = tid >> 4;                 // k sub-quad (k = kq*4 .. +3)
  bf16_t b[4][4];                    // b[i][j]: k-offset i, n-offset j
#pragma unroll
  for (int i = 0; i < 4; ++i) {
    float4 v = *(const float4*)(W + (size_t)(k0 + kq * 4 + i) * Nd + n0 + nq * 4);
    b[i][0] = (bf16_t)v.x; b[i][1] = (bf16_t)v.y;
    b[i][2] = (bf16_t)v.z; b[i][3] = (bf16_t)v.w;
  }
#pragma unroll
  for (int j = 0; j < 4; ++j) {
    union { bf16_t e[2]; int q; } p0, p1;
    p0.e[0] = b[0][j]; p0.e[1] = b[1][j];
    p1.e[0] = b[2][j]; p1.e[1] = b[3][j];
    int nrow = nq * 4 + j;
    *(int*)&tileb[nrow * 66 + kq * 4]     = p0.q;
    *(int*)&tileb[nrow * 66 + kq * 4 + 2] = p1.q;
  }
  __syncthreads();
  int n = tid >> 2;                  // 0..63
  int kc = (tid & 3) * 16;           // 0,16,32,48
  union { bf16_t e[16]; int4 q[2]; } pk;
#pragma unroll
  for (int r = 0; r < 8; ++r)
    *(int*)&pk.e[r * 2] = *(const int*)&tileb[n * 66 + kc + r * 2];
  int4* outp = (int4*)(WT + (size_t)(n0 + n) * Kd + k0 + kc);
  outp[0] = pk.q[0];
  outp[1] = pk.q[1];
}

// ------------------------------------------- MFMA bf16 GEMM, 128x128 tile
// m97 structure + 2-buffer LDS prefetch (R5/R8-verified).
__global__ __launch_bounds__(256) void mgemm_kernel(
    const __hip_bfloat16* __restrict__ A, const __hip_bfloat16* __restrict__ BT,
    const float* __restrict__ Cadd, float* __restrict__ C,
    int M, int N, int K,
    const int* __restrict__ counts, const int* __restrict__ offsets,
    const int* __restrict__ tok, int a_comp,
    const __hip_bfloat16* __restrict__ As2, const __hip_bfloat16* __restrict__ BTs2,
    float* __restrict__ Cs2) {
  __shared__ __align__(16) bf16_t Asd[2][128 * 32];   // 2 x 8 KB
  __shared__ __align__(16) bf16_t Bsd[2][128 * 32];
  __shared__ int rowmap[128];
  int e = blockIdx.z;
  bool sh = (counts != nullptr) && (e == NE);
  int cnt = sh ? M : (counts ? counts[e] : M);
  int bm = blockIdx.y * 128;
  if (bm >= cnt) return;
  int bn = blockIdx.x * 128;
  int obase = sh ? 0 : (offsets ? offsets[e] : 0);
  const bf16_t* Ab = sh ? (const bf16_t*)As2 : (const bf16_t*)A;
  const bf16_t* BTe = sh ? (const bf16_t*)BTs2 : ((const bf16_t*)BT + (size_t)e * N * K);
  float* Cp = sh ? Cs2 : C;
  const int* toke = (!sh && tok) ? tok + e * S : nullptr;
  int acompe = sh ? 0 : a_comp;
  int tid = threadIdx.x;
  if (tid < 128) {
    int gp = bm + tid;
    int cp = gp < cnt ? gp : cnt - 1;
    rowmap[tid] = toke ? toke[cp] : (acompe ? obase + cp : cp);
  }
  __syncthreads();
  int wave = tid >> 6, lane = tid & 63;
  int quad = lane >> 4, l16 = lane & 15;
  int wm = wave >> 1, wn = wave & 1;
  int srow = tid >> 2, scol = (tid & 3) * 8;
  size_t aoff0 = (size_t)rowmap[srow] * K + scol;
  size_t aoff1 = (size_t)rowmap[64 + srow] * K + scol;
  size_t boff0 = (size_t)(bn + srow) * K + scol;
  size_t boff1 = (size_t)(bn + 64 + srow) * K + scol;
  f32x4 acc[4][4];
#pragma unroll
  for (int i = 0; i < 4; ++i)
#pragma unroll
    for (int j = 0; j < 4; ++j) acc[i][j] = (f32x4){0.f, 0.f, 0.f, 0.f};

  // prologue: stage k0=0 into buf 0
  {
    char* AsB = (char*)Asd[0] + wave * 1024;
    char* BsB = (char*)Bsd[0] + wave * 1024;
    gll16(Ab + aoff0, AsB);
    gll16(Ab + aoff1, AsB + 4096);
    gll16(BTe + boff0, BsB);
    gll16(BTe + boff1, BsB + 4096);
  }
  for (int k0 = 0; k0 < K; k0 += 32) {
    int cur = (k0 >> 5) & 1;
    __syncthreads();                         // buf[cur] staged; prev reads done
    if (k0 + 32 < K) {                       // prefetch next into buf[cur^1]
      char* AsB = (char*)Asd[cur ^ 1] + wave * 1024;
      char* BsB = (char*)Bsd[cur ^ 1] + wave * 1024;
      gll16(Ab + aoff0 + k0 + 32, AsB);
      gll16(Ab + aoff1 + k0 + 32, AsB + 4096);
      gll16(BTe + boff0 + k0 + 32, BsB);
      gll16(BTe + boff1 + k0 + 32, BsB + 4096);
    }
    I4B8 af[4], bfr[4];
#pragma unroll
    for (int i = 0; i < 4; ++i)
      af[i].i = *(const int4*)(Asd[cur] + (wm * 64 + i * 16 + l16) * 32 + quad * 8);
#pragma unroll
    for (int j = 0; j < 4; ++j)
      bfr[j].i = *(const int4*)(Bsd[cur] + (wn * 64 + j * 16 + l16) * 32 + quad * 8);
#pragma unroll
    for (int i = 0; i < 4; ++i)
#pragma unroll
      for (int j = 0; j < 4; ++j)
        acc[i][j] = __builtin_amdgcn_mfma_f32_16x16x32_bf16(af[i].v, bfr[j].v, acc[i][j], 0, 0, 0);
  }
#pragma unroll
  for (int i = 0; i < 4; ++i) {
#pragma unroll
    for (int r = 0; r < 4; ++r) {
      int trow = wm * 64 + i * 16 + quad * 4 + r;
      int gp = bm + trow;
      if (gp < cnt) {
        size_t rowb = (size_t)(obase + gp) * N;
#pragma unroll
        for (int j = 0; j < 4; ++j) {
          int col = bn + wn * 64 + j * 16 + l16;
          size_t idx = rowb + col;
          Cp[idx] = acc[i][j][r] + (Cadd ? Cadd[idx] : 0.f);
        }
      }
    }
  }
}

// ------------------------------------------- dense MFMA GEMM, 128x64 tile (fp32 out)
// For under-gridded dense GEMMs (qkv: 384 blocks, wo: 256 blocks vs 192/128 at BN=128).
__global__ __launch_bounds__(256) void mgemm_n64_kernel(
    const __hip_bfloat16* __restrict__ A, const __hip_bfloat16* __restrict__ BT,
    const float* __restrict__ Cadd, float* __restrict__ C,
    int M, int N, int K) {
  __shared__ __align__(16) bf16_t Asd[2][128 * 32];   // 2 x 8 KB
  __shared__ __align__(16) bf16_t Bsd[2][64 * 32];    // 2 x 4 KB
  int bm = blockIdx.y * 128;
  int bn = blockIdx.x * 64;
  int tid = threadIdx.x;
  int wave = tid >> 6, lane = tid & 63;
  int quad = lane >> 4, l16 = lane & 15;
  int wm = wave >> 1, wn = wave & 1;
  int srow = tid >> 2, scol = (tid & 3) * 8;
  size_t aoff0 = (size_t)(bm + srow) * K + scol;
  size_t aoff1 = (size_t)(bm + 64 + srow) * K + scol;
  size_t boff = (size_t)(bn + srow) * K + scol;
  const bf16_t* Ab = (const bf16_t*)A;
  const bf16_t* Bb = (const bf16_t*)BT;
  f32x4 acc[4][2];
#pragma unroll
  for (int i = 0; i < 4; ++i)
#pragma unroll
    for (int j = 0; j < 2; ++j) acc[i][j] = (f32x4){0.f, 0.f, 0.f, 0.f};
  {
    char* AsB = (char*)Asd[0] + wave * 1024;
    gll16(Ab + aoff0, AsB);
    gll16(Ab + aoff1, AsB + 4096);
    gll16(Bb + boff, (char*)Bsd[0] + wave * 1024);
  }
  for (int k0 = 0; k0 < K; k0 += 32) {
    int cur = (k0 >> 5) & 1;
    __syncthreads();
    if (k0 + 32 < K) {
      char* AsB = (char*)Asd[cur ^ 1] + wave * 1024;
      gll16(Ab + aoff0 + k0 + 32, AsB);
      gll16(Ab + aoff1 + k0 + 32, AsB + 4096);
      gll16(Bb + boff + k0 + 32, (char*)Bsd[cur ^ 1] + wave * 1024);
    }
    I4B8 af[4], bf[2];
#pragma unroll
    for (int i = 0; i < 4; ++i)
      af[i].i = *(const int4*)(Asd[cur] + (wm * 64 + i * 16 + l16) * 32 + quad * 8);
#pragma unroll
    for (int j = 0; j < 2; ++j)
      bf[j].i = *(const int4*)(Bsd[cur] + (wn * 32 + j * 16 + l16) * 32 + quad * 8);
#pragma unroll
    for (int i = 0; i < 4; ++i)
#pragma unroll
      for (int j = 0; j < 2; ++j)
        acc[i][j] = __builtin_amdgcn_mfma_f32_16x16x32_bf16(af[i].v, bf[j].v, acc[i][j], 0, 0, 0);
  }
#pragma unroll
  for (int i = 0; i < 4; ++i) {
#pragma unroll
    for (int r = 0; r < 4; ++r) {
      int gp = bm + wm * 64 + i * 16 + quad * 4 + r;
      size_t rowb = (size_t)gp * N;
#pragma unroll
      for (int j = 0; j < 2; ++j) {
        int col = bn + wn * 32 + j * 16 + l16;
        size_t idx = rowb + col;
        C[idx] = acc[i][j][r] + (Cadd ? Cadd[idx] : 0.f);
      }
    }
  }
}

// ------------------------------------------- dual-B MFMA GEMM + silu, 128x64 tile
// R11/R12-verified BN=64 version (local optimum).
__global__ __launch_bounds__(256) void mgemm_gu_kernel(
    const __hip_bfloat16* __restrict__ A, const __hip_bfloat16* __restrict__ BTg,
    const __hip_bfloat16* __restrict__ BTu, __hip_bfloat16* __restrict__ act,
    int M, int N, int K,
    const int* __restrict__ counts, const int* __restrict__ offsets,
    const int* __restrict__ tok,
    const __hip_bfloat16* __restrict__ BTgs, const __hip_bfloat16* __restrict__ BTus,
    __hip_bfloat16* __restrict__ acts) {
  __shared__ __align__(16) bf16_t Asd[2][128 * 32];   // 2 x 8 KB
  __shared__ __align__(16) bf16_t Bgd[2][64 * 32];    // 2 x 4 KB
  __shared__ __align__(16) bf16_t Bud[2][64 * 32];    // 2 x 4 KB
  __shared__ int rowmap[128];
  int e = blockIdx.z;
  bool sh = (counts != nullptr) && (e == NE);
  int cnt = sh ? M : (counts ? counts[e] : M);
  int bm = blockIdx.y * 128;
  if (bm >= cnt) return;
  int bn = blockIdx.x * 64;
  const bf16_t* Ab = (const bf16_t*)A;
  const bf16_t* Bg = sh ? (const bf16_t*)BTgs : ((const bf16_t*)BTg + (size_t)e * N * K);
  const bf16_t* Bu = sh ? (const bf16_t*)BTus : ((const bf16_t*)BTu + (size_t)e * N * K);
  bf16_t* outp = sh ? (bf16_t*)acts : (bf16_t*)act;
  int obase = sh ? 0 : (offsets ? offsets[e] : 0);
  const int* toke = (!sh && tok) ? tok + e * S : nullptr;
  int tid = threadIdx.x;
  if (tid < 128) {
    int gp = bm + tid;
    int cp = gp < cnt ? gp : cnt - 1;
    rowmap[tid] = toke ? toke[cp] : cp;
  }
  __syncthreads();
  int wave = tid >> 6, lane = tid & 63;
  int quad = lane >> 4, l16 = lane & 15;
  int wm = wave >> 1, wn = wave & 1;
  int srow = tid >> 2, scol = (tid & 3) * 8;
  size_t aoff0 = (size_t)rowmap[srow] * K + scol;
  size_t aoff1 = (size_t)rowmap[64 + srow] * K + scol;
  size_t boff = (size_t)(bn + srow) * K + scol;
  f32x4 accg[4][2], accu[4][2];
#pragma unroll
  for (int i = 0; i < 4; ++i)
#pragma unroll
    for (int j = 0; j < 2; ++j) {
      accg[i][j] = (f32x4){0.f, 0.f, 0.f, 0.f};
      accu[i][j] = (f32x4){0.f, 0.f, 0.f, 0.f};
    }
  // prologue
  {
    char* AsB = (char*)Asd[0] + wave * 1024;
    gll16(Ab + aoff0, AsB);
    gll16(Ab + aoff1, AsB + 4096);
    gll16(Bg + boff, (char*)Bgd[0] + wave * 1024);
    gll16(Bu + boff, (char*)Bud[0] + wave * 1024);
  }
  for (int k0 = 0; k0 < K; k0 += 32) {
    int cur = (k0 >> 5) & 1;
    __syncthreads();
    if (k0 + 32 < K) {
      char* AsB = (char*)Asd[cur ^ 1] + wave * 1024;
      gll16(Ab + aoff0 + k0 + 32, AsB);
      gll16(Ab + aoff1 + k0 + 32, AsB + 4096);
      gll16(Bg + boff + k0 + 32, (char*)Bgd[cur ^ 1] + wave * 1024);
      gll16(Bu + boff + k0 + 32, (char*)Bud[cur ^ 1] + wave * 1024);
    }
    I4B8 af[4], bg[2], bu[2];
#pragma unroll
    for (int i = 0; i < 4; ++i)
      af[i].i = *(const int4*)(Asd[cur] + (wm * 64 + i * 16 + l16) * 32 + quad * 8);
#pragma unroll
    for (int j = 0; j < 2; ++j) {
      bg[j].i = *(const int4*)(Bgd[cur] + (wn * 32 + j * 16 + l16) * 32 + quad * 8);
      bu[j].i = *(const int4*)(Bud[cur] + (wn * 32 + j * 16 + l16) * 32 + quad * 8);
    }
#pragma unroll
    for (int i = 0; i < 4; ++i)
#pragma unroll
      for (int j = 0; j < 2; ++j) {
        accg[i][j] = __builtin_amdgcn_mfma_f32_16x16x32_bf16(af[i].v, bg[j].v, accg[i][j], 0, 0, 0);
        accu[i][j] = __builtin_amdgcn_mfma_f32_16x16x32_bf16(af[i].v, bu[j].v, accu[i][j], 0, 0, 0);
      }
  }
#pragma unroll
  for (int i = 0; i < 4; ++i) {
#pragma unroll
    for (int r = 0; r < 4; ++r) {
      int trow = wm * 64 + i * 16 + quad * 4 + r;
      int gp = bm + trow;
      if (gp < cnt) {
        size_t rowb = (size_t)(obase + gp) * N;
#pragma unroll
        for (int j = 0; j < 2; ++j) {
          int col = bn + wn * 32 + j * 16 + l16;
          float g = accg[i][j][r], uu = accu[i][j][r];
          float sg = g / (1.f + __expf(-g));
          outp[rowb + col] = __float2bfloat16(sg * uu);
        }
      }
    }
  }
}

// --------------------------------------------- q/k head rmsnorm + RoPE + bf16 cast
// grid (S, 6): y<5 = q/k heads; y==5 = V transpose tiles (fp32 qkv -> bf16 vT[256][2048]).
__global__ void qkv_post_kernel(const float* __restrict__ qkv,
                                const float* __restrict__ qw, const float* __restrict__ kw,
                                const float* __restrict__ cosb, const float* __restrict__ sinb,
                                __hip_bfloat16* __restrict__ qout,
                                __hip_bfloat16* __restrict__ kout,
                                __hip_bfloat16* __restrict__ vT) {
  __shared__ float tile[32][33];
  if (blockIdx.y == 5) {                     // V transpose: 512 tiles
    int bx = blockIdx.x;
    if (bx < 512) {
      int t0 = (bx & 63) * 32;
      int c0 = (bx >> 6) * 32;
      int tx = threadIdx.x & 31, ty = threadIdx.x >> 5;
#pragma unroll
      for (int i = 0; i < 4; ++i)
        tile[ty + i * 8][tx] = qkv[(size_t)(t0 + ty + i * 8) * QKV_N + (NH + NKV) * HD + c0 + tx];
      __syncthreads();
#pragma unroll
      for (int i = 0; i < 4; ++i)
        vT[(size_t)(c0 + ty + i * 8) * S + t0 + tx] = __float2bfloat16(tile[tx][ty + i * 8]);
    }
    return;
  }
  int t = blockIdx.x;
  int u = blockIdx.y * 4 + (threadIdx.x >> 6);
  int lane = threadIdx.x & 63;
  bool isq = (u < NH);
  int h = isq ? u : (u - NH);
  size_t src = (size_t)t * QKV_N + (isq ? (h * HD) : (NH * HD + h * HD)) + lane;
  float xv = qkv[src];
  float ss = xv * xv;
#pragma unroll
  for (int off = 32; off; off >>= 1) ss += __shfl_xor(ss, off);
  float r = rsqrtf(ss * (1.f / 64.f) + EPS);
  float xn = xv * r * (isq ? qw[lane] : kw[lane]);
  float other = __shfl_xor(xn, 32);
  float rot = (lane < 32) ? -other : other;
  float res = xn * cosb[t * 64 + lane] + rot * sinb[t * 64 + lane];
  if (isq) qout[(size_t)t * (NH * HD) + h * HD + lane] = __float2bfloat16(res * 0.125f);
  else     kout[(size_t)t * (NKV * HD) + h * HD + lane] = __float2bfloat16(res);
}

// --------------------------------------------- MFMA flash attention v6
// GQA-merged + KV-split-4 + FUSED merge: the 16th (last) block of each qt group
// (4 kvh x 4 z) merges that qt's 16 rows. Per-qt counters (16 atomics/line, NOT
// the R4 convoy). Release: __syncthreads (drains stores) + __threadfence (L2 wb).
__global__ __launch_bounds__(256) void attn_kernel(
    const __hip_bfloat16* __restrict__ qg, const __hip_bfloat16* __restrict__ kg,
    const __hip_bfloat16* __restrict__ vT,
    float* __restrict__ op0, float* __restrict__ op1,
    float* __restrict__ op2, float* __restrict__ op3,
    float* __restrict__ mpart, float* __restrict__ lpart,
    __hip_bfloat16* __restrict__ attn_out, int* __restrict__ qt_ctr) {
  int qt = (int)(gridDim.x - 1) - (int)blockIdx.x;   // heavy tiles first
  int kvh = blockIdx.y;
  int z = blockIdx.z;
  int tid = threadIdx.x;
  int wave = tid >> 6, lane = tid & 63;
  int quad = lane >> 4, l16 = lane & 15;
  int h = kvh * 4 + wave;

  __shared__ __align__(16) int KsI[64 * 36];         // K tile [64 k][64 d + pad]
  __shared__ __align__(16) int VTI[64 * 36];         // V^T tile [64 d][64 k + pad]
  __shared__ __align__(16) int PsI[4][16 * 36];      // per-wave P [16 q][64 k + pad]
  __shared__ int lastFlag;

  float* opz = (z == 0) ? op0 : (z == 1) ? op1 : (z == 2) ? op2 : op3;
  float* mp = mpart + (size_t)z * S * NH;
  float* lp = lpart + (size_t)z * S * NH;

  int nb = (qt >> 1) + 1;            // valid 32-blocks of kv
  int nt = (nb + 1) >> 1;            // 64-wide tiles
  bool halfm = (nb & 1) != 0;        // last tile only 32 valid
  int lo = (nt * z) >> 2;
  int hi = (nt * (z + 1)) >> 2;

  if (lo >= hi) {                    // empty chunk: zero partials
    int row = qt * 16 + (tid >> 4);
    float* od = opz + (size_t)row * (NH * HD) + kvh * 256 + (tid & 15) * 16;
    int4 zz = {0, 0, 0, 0};
#pragma unroll
    for (int i = 0; i < 4; ++i) *(int4*)(od + i * 4) = zz;
    if (tid < 64) {
      int rr = qt * 16 + (tid >> 2), hh = kvh * 4 + (tid & 3);
      mp[(size_t)rr * NH + hh] = -1e30f;
      lp[(size_t)rr * NH + hh] = 0.f;
    }
  } else {
    I4B8 qf[2];
#pragma unroll
    for (int ch = 0; ch < 2; ++ch)
      qf[ch].i = *(const int4*)((const abf16*)qg +
          (size_t)(qt * 16 + l16) * (NH * HD) + h * HD + ch * 32 + quad * 8);

    I4B8 ones;
    ones.i = (int4){0x3F803F80, 0x3F803F80, 0x3F803F80, 0x3F803F80};   // 8x bf16 1.0

    float m_r[4];
    f32x4 o[4], o4;
#pragma unroll
    for (int r = 0; r < 4; ++r) m_r[r] = -1e30f;
#pragma unroll
    for (int sub = 0; sub < 4; ++sub) o[sub] = (f32x4){0.f, 0.f, 0.f, 0.f};
    o4 = (f32x4){0.f, 0.f, 0.f, 0.f};

    int sp = tid >> 3, sc = tid & 7;   // staging: 32 rows x 8 octets (x2 halves)
    const abf16* kb = (const abf16*)kg;
    const abf16* vb = (const abf16*)vT;

    // T14 prologue: load first tile into regs
    int4 rk0 = *(const int4*)(kb + (size_t)(lo * 64 + sp) * (NKV * HD) + kvh * HD + sc * 8);
    int4 rk1 = *(const int4*)(kb + (size_t)(lo * 64 + 32 + sp) * (NKV * HD) + kvh * HD + sc * 8);
    int4 rv0 = *(const int4*)(vb + (size_t)(kvh * HD + sp) * S + lo * 64 + sc * 8);
    int4 rv1 = *(const int4*)(vb + (size_t)(kvh * HD + 32 + sp) * S + lo * 64 + sc * 8);

    for (int kc = lo; kc < hi; ++kc) {
      // ---- write staged regs to LDS (prev compute done via loop-bottom barrier)
      *(int4*)&KsI[sp * 36 + sc * 4] = rk0;
      *(int4*)&KsI[(sp + 32) * 36 + sc * 4] = rk1;
      *(int4*)&VTI[sp * 36 + sc * 4] = rv0;
      *(int4*)&VTI[(sp + 32) * 36 + sc * 4] = rv1;
      __syncthreads();

      // ---- issue next tile loads (latency hides under compute below)
      if (kc + 1 < hi) {
        rk0 = *(const int4*)(kb + (size_t)((kc + 1) * 64 + sp) * (NKV * HD) + kvh * HD + sc * 8);
        rk1 = *(const int4*)(kb + (size_t)((kc + 1) * 64 + 32 + sp) * (NKV * HD) + kvh * HD + sc * 8);
        rv0 = *(const int4*)(vb + (size_t)(kvh * HD + sp) * S + (kc + 1) * 64 + sc * 8);
        rv1 = *(const int4*)(vb + (size_t)(kvh * HD + 32 + sp) * S + (kc + 1) * 64 + sc * 8);
      }

      // ---- QK^T: 16 q-rows x 64 k
      f32x4 s[4];
#pragma unroll
      for (int sub = 0; sub < 4; ++sub) s[sub] = (f32x4){0.f, 0.f, 0.f, 0.f};
      __builtin_amdgcn_s_setprio(1);
#pragma unroll
      for (int sub = 0; sub < 4; ++sub)
#pragma unroll
        for (int ch = 0; ch < 2; ++ch) {
          I4B8 ku;
          ku.i = *(const int4*)&KsI[(sub * 16 + l16) * 36 + ch * 16 + quad * 4];
          s[sub] = __builtin_amdgcn_mfma_f32_16x16x32_bf16(qf[ch].v, ku.v, s[sub], 0, 0, 0);
        }
      __builtin_amdgcn_s_setprio(0);
      if (halfm && kc == nt - 1) {
#pragma unroll
        for (int r = 0; r < 4; ++r) { s[2][r] = -1e30f; s[3][r] = -1e30f; }
      }

      // ---- online softmax: max-reduce + exp; sums come from ones-MFMA
      abf16* pw = (abf16*)PsI[wave];
#pragma unroll
      for (int r = 0; r < 4; ++r) {
        float v = fmaxf(fmaxf(s[0][r], s[1][r]), fmaxf(s[2][r], s[3][r]));
#pragma unroll
        for (int off = 1; off < 16; off <<= 1) v = fmaxf(v, __shfl_xor(v, off));
        float mx = fmaxf(m_r[r], v);
        float al = __expf(m_r[r] - mx);
        m_r[r] = mx;
        float p0 = __expf(s[0][r] - mx);
        float p1 = __expf(s[1][r] - mx);
        float p2 = __expf(s[2][r] - mx);
        float p3 = __expf(s[3][r] - mx);
        int prow = quad * 4 + r;
        pw[prow * 72 + l16]      = (bf16_t)p0;
        pw[prow * 72 + 16 + l16] = (bf16_t)p1;
        pw[prow * 72 + 32 + l16] = (bf16_t)p2;
        pw[prow * 72 + 48 + l16] = (bf16_t)p3;
        o4[r] *= al;
#pragma unroll
        for (int sub = 0; sub < 4; ++sub) o[sub][r] *= al;
      }

      // ---- PV: P(16x64) x V(64x64) + ones-column for row sums
      I4B8 pu[2];
#pragma unroll
      for (int ch = 0; ch < 2; ++ch)
        pu[ch].i = *(const int4*)&PsI[wave][l16 * 36 + ch * 16 + quad * 4];
      __builtin_amdgcn_s_setprio(1);
#pragma unroll
      for (int sub = 0; sub < 4; ++sub)
#pragma unroll
        for (int ch = 0; ch < 2; ++ch) {
          I4B8 vf;
          vf.i = *(const int4*)&VTI[(sub * 16 + l16) * 36 + ch * 16 + quad * 4];
          o[sub] = __builtin_amdgcn_mfma_f32_16x16x32_bf16(pu[ch].v, vf.v, o[sub], 0, 0, 0);
        }
#pragma unroll
      for (int ch = 0; ch < 2; ++ch)
        o4 = __builtin_amdgcn_mfma_f32_16x16x32_bf16(pu[ch].v, ones.v, o4, 0, 0, 0);
      __builtin_amdgcn_s_setprio(0);
      __syncthreads();
    }

    // epilogue: write raw partials (normalize at merge)
#pragma unroll
    for (int r = 0; r < 4; ++r) {
      int row = qt * 16 + quad * 4 + r;
      float* od = opz + (size_t)row * (NH * HD) + h * HD;
#pragma unroll
      for (int sub = 0; sub < 4; ++sub)
        od[sub * 16 + l16] = o[sub][r];
      if (l16 == 0) {
        mp[(size_t)row * NH + h] = m_r[r];
        lp[(size_t)row * NH + h] = o4[r];
      }
    }
  }

  // ---- fan-in: last of this qt's 16 blocks merges its 16 rows
  __syncthreads();                       // drain this block's partial stores
  if (tid == 0) {
    __threadfence();                     // release: write back to device scope
    int prev = atomicAdd(&qt_ctr[qt], 1);
    lastFlag = (prev == NKV * 4 - 1);
  }
  __syncthreads();
  if (lastFlag) {
    __threadfence();                     // acquire: invalidate stale caches
    for (int rr = 0; rr < 16; ++rr) {
      int row = qt * 16 + rr;
#pragma unroll
      for (int i = 0; i < 4; ++i) {
        int c = tid + i * 256;
        int hh = c >> 6;
        float m0 = mpart[(size_t)row * NH + hh];
        float m1 = mpart[(size_t)(S + row) * NH + hh];
        float m2 = mpart[(size_t)(2 * S + row) * NH + hh];
        float m3 = mpart[(size_t)(3 * S + row) * NH + hh];
        float l0 = lpart[(size_t)row * NH + hh];
        float l1 = lpart[(size_t)(S + row) * NH + hh];
        float l2 = lpart[(size_t)(2 * S + row) * NH + hh];
        float l3 = lpart[(size_t)(3 * S + row) * NH + hh];
        float M = fmaxf(fmaxf(m0, m1), fmaxf(m2, m3));
        float a0 = __expf(m0 - M), a1 = __expf(m1 - M);
        float a2 = __expf(m2 - M), a3 = __expf(m3 - M);
        float l = l0 * a0 + l1 * a1 + l2 * a2 + l3 * a3;
        size_t idx = (size_t)row * (NH * HD) + c;
        float v = (op0[idx] * a0 + op1[idx] * a1 + op2[idx] * a2 + op3[idx] * a3) / l;
        attn_out[idx] = __float2bfloat16(v);
      }
    }
  }
}

// ---------------------------------------------------------------- router phase B
// ONE block, 1024 threads. Ballot-aggregated LDS counters -> tok_list/topk_pos.
// (Kept as a separate launch: a fused fan-in would be 2048 atomics on one line —
//  the R4 convoy.)
__global__ __launch_bounds__(1024) void router_place_kernel(
    const int* __restrict__ topk_e, int* __restrict__ counts, int* __restrict__ offsets,
    int* __restrict__ tok_list, int* __restrict__ topk_pos) {
  __shared__ int lcnt[NE];
  int tid = threadIdx.x;
  int lane = tid & 63;
  if (tid < NE) lcnt[tid] = 0;
  __syncthreads();
#pragma unroll
  for (int r = 0; r < 2; ++r) {
    int t = r * 1024 + tid;
#pragma unroll
    for (int s = 0; s < 2; ++s) {
      int e = topk_e[2 * t + s];
      int pos = 0;
#pragma unroll
      for (int x = 0; x < NE; ++x) {
        unsigned long long mask = __ballot(e == x);
        if (mask) {
          int leader = __ffsll((unsigned long long)mask) - 1;
          int cnt = __popcll(mask);
          int base = 0;
          if (lane == leader) base = atomicAdd(&lcnt[x], cnt);
          base = __shfl(base, leader);
          if (e == x)
            pos = base + __popcll(mask & ((1ull << lane) - 1ull));
        }
      }
      topk_pos[2 * t + s] = pos;
      tok_list[e * S + pos] = t;
    }
  }
  __syncthreads();
  if (tid == 0) {
    int acc = 0;
    for (int e = 0; e < NE; ++e) { offsets[e] = acc; counts[e] = lcnt[e]; acc += lcnt[e]; }
  }
}

// ---------------------------------------------------------------- final add
__global__ void final_kernel(const float* __restrict__ x, const float* __restrict__ sout,
                             const float* __restrict__ eo,
                             const int* __restrict__ topk_e, const int* __restrict__ topk_pos,
                             const float* __restrict__ topk_w, const int* __restrict__ offsets,
                             float* __restrict__ out) {
  int t = blockIdx.x;
  int tid = threadIdx.x;
  int e0 = topk_e[2 * t], e1 = topk_e[2 * t + 1];
  size_t r0 = (size_t)offsets[e0] + topk_pos[2 * t];
  size_t r1 = (size_t)offsets[e1] + topk_pos[2 * t + 1];
  float w0 = topk_w[2 * t], w1 = topk_w[2 * t + 1];
#pragma unroll
  for (int i = 0; i < 4; ++i) {
    int d = tid + i * 256;
    size_t idx = (size_t)t * D + d;
    out[idx] = x[idx] + sout[idx] + w0 * eo[r0 * D + d] + w1 * eo[r1 * D + d];
  }
}

extern "C" void kernel_launch(void* const* d_in, const int* in_sizes, int n_in,
                              void* d_out, int out_size, void* d_ws, size_t ws_size,
                              hipStream_t stream) {
  const float* hidden  = (const float*)d_in[0];
  const float* cosb    = (const float*)d_in[1];
  const float* sinb    = (const float*)d_in[2];
  const float* w_qkv   = (const float*)d_in[3];
  const float* w_o     = (const float*)d_in[4];
  const float* q_norm  = (const float*)d_in[5];
  const float* k_norm  = (const float*)d_in[6];
  const float* in_ln   = (const float*)d_in[7];
  const float* post_ln = (const float*)d_in[8];
  const float* router_w= (const float*)d_in[9];
  const float* w_gate  = (const float*)d_in[10];
  const float* w_up    = (const float*)d_in[11];
  const float* w_down  = (const float*)d_in[12];
  const float* ws_gate = (const float*)d_in[13];
  const float* ws_up   = (const float*)d_in[14];
  const float* ws_down = (const float*)d_in[15];
  float* out = (float*)d_out;
  float* ws = (float*)d_ws;

  typedef __hip_bfloat16 hbf;
  // weights (bf16)
  hbf* wqkvT = (hbf*)(ws);                      // 1.5M el
  hbf* woT   = (hbf*)(ws +  768 * 1024);        // 1M el
  hbf* wgT   = (hbf*)(ws + 1280 * 1024);        // 8M el
  hbf* wuT   = (hbf*)(ws + 5376 * 1024);        // 8M el
  hbf* wdT   = (hbf*)(ws + 9472 * 1024);        // 8M el
  hbf* wsgT  = (hbf*)(ws + 13568 * 1024);       // 1M el
  hbf* wsuT  = (hbf*)(ws + 14080 * 1024);       // 1M el
  hbf* wsdT  = (hbf*)(ws + 14592 * 1024);       // 1M el
  // activations
  hbf*   hb      = (hbf*)(ws + 15104 * 1024);   // [15104K,16128K) floats, dead after qkv GEMM
  float* qkv     = ws + 16128 * 1024;           // [16128K,19200K), dead after qkv_post
  hbf*   qbB     = (hbf*)(ws + 19200 * 1024);
  hbf*   kbB     = (hbf*)(ws + 20224 * 1024);
  hbf*   vTb     = (hbf*)(ws + 20480 * 1024);   // V^T [256][2048]
  hbf*   attnb16 = (hbf*)(ws + 20736 * 1024);
  float* x       = ws + 22784 * 1024;           // 2M fl (written by wo GEMM, after merge)
  hbf*   h2b     = (hbf*)(ws + 26880 * 1024);   // written after attention
  hbf*   act     = (hbf*)(ws + 16128 * 1024);   // 4096x1024 bf16, aliases dead qkv
  float* eo      = ws + 18176 * 1024;           // 4096x1024 fp32, aliases dead q/k/v
  hbf*   sact    = (hbf*)(ws + 27904 * 1024);   // 2048x1024 bf16 (written by gu)
  float* sout    = ws + 28928 * 1024;           // 2048x1024 fp32 (written by down GEMM)
  // attention partials (live only attn -> merge; all regions dead during attention):
  float* mpart   = ws + 15104 * 1024;           // [4][S][NH]  (aliases dead hb)
  float* lpart   = mpart + 4 * S * NH;
  float* opart0  = ws + 16128 * 1024;           // aliases dead qkv
  float* opart1  = ws + 22784 * 1024;           // aliases x (written later)
  float* opart2  = ws + 28928 * 1024;           // aliases sout (written later)
  float* opart3  = ws + 26880 * 1024;           // aliases h2b+sact (written later)
  int* counts   = (int*)(ws + 30976 * 1024);
  int* offsets  = counts + NE;
  int* tok_list = offsets + NE;
  int* topk_e   = tok_list + NE * S;
  int* topk_pos = topk_e + 2 * S;
  float* topk_w = (float*)(topk_pos + 2 * S);
  int* qt_ctr   = (int*)(topk_w + 2 * S);       // [128] per-qt merge counters

  dim3 b256(256);
  // transposes (64x64 tiles) + pre-attention rmsnorm + qt_ctr reset (z==29)
  transpose_all_kernel<<<dim3(24, 16, 30), b256, 0, stream>>>(
      w_qkv, w_o, w_gate, w_up, w_down, ws_gate, ws_up, ws_down,
      wqkvT, woT, wgT, wuT, wdT, wsgT, wsuT, wsdT,
      hidden, in_ln, hb, qt_ctr);
  // attention block
  mgemm_n64_kernel<<<dim3(QKV_N/64, S/128), b256, 0, stream>>>(hb, wqkvT, nullptr, qkv,
      S, QKV_N, D);
  qkv_post_kernel<<<dim3(S, 6), b256, 0, stream>>>(qkv, q_norm, k_norm, cosb, sinb, qbB, kbB, vTb);
  attn_kernel<<<dim3(S/16, NKV, 4), b256, 0, stream>>>(qbB, kbB, vTb,
      opart0, opart1, opart2, opart3, mpart, lpart, attnb16, qt_ctr);
  mgemm_n64_kernel<<<dim3(D/64, S/128), b256, 0, stream>>>(attnb16, woT, hidden, x,
      S, D, D);
  // MoE block (shared expert merged as z == NE)
  rmsnorm_router_kernel<<<S, b256, 0, stream>>>(x, post_ln, router_w, h2b, topk_e, topk_w);
  router_place_kernel<<<1, 1024, 0, stream>>>(topk_e, counts, offsets, tok_list, topk_pos);
  mgemm_gu_kernel<<<dim3(NI/64, S/128, NE + 1), b256, 0, stream>>>(h2b, wgT, wuT, act,
      S, NI, D, counts, offsets, tok_list, wsgT, wsuT, sact);
  mgemm_kernel<<<dim3(D/128, S/128, NE + 1), b256, 0, stream>>>(act, wdT, nullptr, eo,
      S, D, NI, counts, offsets, nullptr, 1, sact, wsdT, sout);
  final_kernel<<<S, b256, 0, stream>>>(x, sout, eo, topk_e, topk_pos, topk_w, offsets, out);
}

// Round 17
// 394.593 us; speedup vs baseline: 1.2574x; 1.2574x over previous
//
#include <hip/hip_runtime.h>
#include <hip/hip_bf16.h>
#include <math.h>

#define S 2048
#define D 1024
#define NH 16
#define NKV 4
#define HD 64
#define QKV_N 1536          // (NH + 2*NKV) * HD
#define NE 8
#define NI 1024
#define EPS 1e-6f

typedef __bf16 bf16_t;
typedef __bf16 __attribute__((may_alias)) abf16;
typedef __attribute__((ext_vector_type(8))) __bf16 bf16x8;
typedef __attribute__((ext_vector_type(4))) float f32x4;
union I4B8 { int4 i; bf16x8 v; bf16_t e[8]; };

// async global->LDS, 16B per lane. LDS dest must be wave-uniform base
// (HW adds lane*16); global src is per-lane.
__device__ __forceinline__ void gll16(const void* g, void* l) {
  __builtin_amdgcn_global_load_lds(
      (const __attribute__((address_space(1))) void*)g,
      (__attribute__((address_space(3))) void*)l, 16, 0, 0);
}

// NOTE (R9): XCD block swizzle REGRESSED 2x (sparse expert grids -> 2/8 XCDs). Don't re-add.
// NOTE (R12): transpose LDS bank conflicts were NOT the limiter (fixed, dur unchanged).
// NOTE (R13): 256-k transpose tiles REGRESSED (occupancy/MLP loss). R12's 64x64 pattern
//             is the accepted floor for the transpose.
// NOTE (R14): gu BN=128 REGRESSED (1 block/CU). Occupancy-for-intensity trades lost 3x.
// NOTE (R16): fusing attn_merge via last-block + __threadfence REGRESSED 100us:
//             2048 device-scope fences forced partials to HBM (WRITE 4->41MB).
//             Kernel-boundary ordering is FREE vs per-block device fences at MB scale.

// ---------------------------- rmsnorm + router logits/top2 fused (MoE pre-pass)
__global__ void rmsnorm_router_kernel(const float* __restrict__ in, const float* __restrict__ w,
                                      const float* __restrict__ rw,
                                      __hip_bfloat16* __restrict__ out16,
                                      int* __restrict__ topk_e, float* __restrict__ topk_w) {
  int t = blockIdx.x;
  int tid = threadIdx.x;
  const float* row = in + (size_t)t * D;
  float v[4];
  float ss = 0.f;
#pragma unroll
  for (int i = 0; i < 4; ++i) {
    v[i] = row[tid + i * 256];
    ss += v[i] * v[i];
  }
#pragma unroll
  for (int off = 32; off; off >>= 1) ss += __shfl_xor(ss, off);
  __shared__ float wsum[4];
  __shared__ float pl[4][NE];
  int wave = tid >> 6, lane = tid & 63;
  if (lane == 0) wsum[wave] = ss;
  __syncthreads();
  float tot = wsum[0] + wsum[1] + wsum[2] + wsum[3];
  float r = rsqrtf(tot / (float)D + EPS);
  float p[NE] = {};
#pragma unroll
  for (int i = 0; i < 4; ++i) {
    int d = tid + i * 256;
    float val = v[i] * r * w[d];
    out16[(size_t)t * D + d] = __float2bfloat16(val);
    const float* rwd = rw + (size_t)d * NE;
#pragma unroll
    for (int e = 0; e < NE; ++e) p[e] += val * rwd[e];
  }
#pragma unroll
  for (int off = 32; off; off >>= 1)
#pragma unroll
    for (int e = 0; e < NE; ++e) p[e] += __shfl_xor(p[e], off);
  if (lane == 0)
#pragma unroll
    for (int e = 0; e < NE; ++e) pl[wave][e] = p[e];
  __syncthreads();
  if (tid == 0) {
    float q[NE];
#pragma unroll
    for (int e = 0; e < NE; ++e) q[e] = pl[0][e] + pl[1][e] + pl[2][e] + pl[3][e];
    float mx = q[0];
#pragma unroll
    for (int e = 1; e < NE; ++e) mx = fmaxf(mx, q[e]);
    float ex[NE];
#pragma unroll
    for (int e = 0; e < NE; ++e) ex[e] = __expf(q[e] - mx);
    int e0 = 0;
#pragma unroll
    for (int e = 1; e < NE; ++e) if (ex[e] > ex[e0]) e0 = e;
    int e1 = (e0 == 0) ? 1 : 0;
#pragma unroll
    for (int e = 0; e < NE; ++e) if (e != e0 && ex[e] > ex[e1]) e1 = e;
    float w0 = ex[e0] / (ex[e0] + ex[e1]);
    float w1 = ex[e1] / (ex[e0] + ex[e1]);
    topk_e[2 * t] = e0;  topk_e[2 * t + 1] = e1;
    topk_w[2 * t] = w0;  topk_w[2 * t + 1] = w1;
  }
}

// ------------------------------------------- ALL weight transposes + rmsnorm, ONE launch
// z<29: 64x64 tiles, register-transposed 4x4 sub-blocks (R12-verified floor).
// z==29: pre-attention rmsnorm (6 tokens per block over the 24x16 grid).
__global__ void transpose_all_kernel(
    const float* __restrict__ w_qkv, const float* __restrict__ w_o,
    const float* __restrict__ w_gate, const float* __restrict__ w_up,
    const float* __restrict__ w_down, const float* __restrict__ ws_gate,
    const float* __restrict__ ws_up, const float* __restrict__ ws_down,
    __hip_bfloat16* wqkvT, __hip_bfloat16* woT, __hip_bfloat16* wgT,
    __hip_bfloat16* wuT, __hip_bfloat16* wdT, __hip_bfloat16* wsgT,
    __hip_bfloat16* wsuT, __hip_bfloat16* wsdT,
    const float* __restrict__ hidden, const float* __restrict__ in_ln,
    __hip_bfloat16* __restrict__ hb_out) {
  int z = blockIdx.z;
  int tid = threadIdx.x;
  if (z == 29) {                     // fused rmsnorm (pre-attention)
    __shared__ float wsum[4];
    int base = ((int)blockIdx.y * 24 + (int)blockIdx.x) * 6;
    int wave = tid >> 6;
#pragma unroll
    for (int jj = 0; jj < 6; ++jj) {
      int t = base + jj;
      if (t < S) {
        const float* row = hidden + (size_t)t * D;
        float v[4];
        float ss = 0.f;
#pragma unroll
        for (int i = 0; i < 4; ++i) {
          v[i] = row[tid + i * 256];
          ss += v[i] * v[i];
        }
#pragma unroll
        for (int off = 32; off; off >>= 1) ss += __shfl_xor(ss, off);
        if ((tid & 63) == 0) wsum[wave] = ss;
        __syncthreads();
        float tot = wsum[0] + wsum[1] + wsum[2] + wsum[3];
        float r = rsqrtf(tot / (float)D + EPS);
#pragma unroll
        for (int i = 0; i < 4; ++i) {
          int d = tid + i * 256;
          hb_out[(size_t)t * D + d] = __float2bfloat16(v[i] * r * in_ln[d]);
        }
      }
      __syncthreads();               // wsum reuse across tokens
    }
    return;
  }
  __shared__ bf16_t tileb[64 * 66];  // [n][k], stride 66 bf16 (2-way-free banks)
  const float* W; __hip_bfloat16* WT; int Kd, Nd;
  if (z == 0)       { W = w_qkv;  WT = wqkvT; Kd = D;  Nd = QKV_N; }
  else if (z == 1)  { W = w_o;    WT = woT;   Kd = D;  Nd = D; }
  else if (z < 10)  { int e = z - 2;  W = w_gate + (size_t)e * D * NI; WT = wgT + (size_t)e * D * NI; Kd = D;  Nd = NI; }
  else if (z < 18)  { int e = z - 10; W = w_up   + (size_t)e * D * NI; WT = wuT + (size_t)e * D * NI; Kd = D;  Nd = NI; }
  else if (z < 26)  { int e = z - 18; W = w_down + (size_t)e * NI * D; WT = wdT + (size_t)e * NI * D; Kd = NI; Nd = D; }
  else if (z == 26) { W = ws_gate; WT = wsgT; Kd = D;  Nd = NI; }
  else if (z == 27) { W = ws_up;   WT = wsuT; Kd = D;  Nd = NI; }
  else              { W = ws_down; WT = wsdT; Kd = NI; Nd = D; }
  int n0 = blockIdx.x * 64, k0 = blockIdx.y * 64;
  if (n0 >= Nd || k0 >= Kd) return;
  int nq = tid & 15;                 // n sub-quad (n = nq*4 .. +3)
  int kq = tid >> 4;                 // k sub-quad (k = kq*4 .. +3)
  bf16_t b[4][4];                    // b[i][j]: k-offset i, n-offset j
#pragma unroll
  for (int i = 0; i < 4; ++i) {
    float4 v = *(const float4*)(W + (size_t)(k0 + kq * 4 + i) * Nd + n0 + nq * 4);
    b[i][0] = (bf16_t)v.x; b[i][1] = (bf16_t)v.y;
    b[i][2] = (bf16_t)v.z; b[i][3] = (bf16_t)v.w;
  }
#pragma unroll
  for (int j = 0; j < 4; ++j) {
    union { bf16_t e[2]; int q; } p0, p1;
    p0.e[0] = b[0][j]; p0.e[1] = b[1][j];
    p1.e[0] = b[2][j]; p1.e[1] = b[3][j];
    int nrow = nq * 4 + j;
    *(int*)&tileb[nrow * 66 + kq * 4]     = p0.q;
    *(int*)&tileb[nrow * 66 + kq * 4 + 2] = p1.q;
  }
  __syncthreads();
  int n = tid >> 2;                  // 0..63
  int kc = (tid & 3) * 16;           // 0,16,32,48
  union { bf16_t e[16]; int4 q[2]; } pk;
#pragma unroll
  for (int r = 0; r < 8; ++r)
    *(int*)&pk.e[r * 2] = *(const int*)&tileb[n * 66 + kc + r * 2];
  int4* outp = (int4*)(WT + (size_t)(n0 + n) * Kd + k0 + kc);
  outp[0] = pk.q[0];
  outp[1] = pk.q[1];
}

// ------------------------------------------- MFMA bf16 GEMM, 128x128 tile
// m97 structure + 2-buffer LDS prefetch (R5/R8-verified).
__global__ __launch_bounds__(256) void mgemm_kernel(
    const __hip_bfloat16* __restrict__ A, const __hip_bfloat16* __restrict__ BT,
    const float* __restrict__ Cadd, float* __restrict__ C,
    int M, int N, int K,
    const int* __restrict__ counts, const int* __restrict__ offsets,
    const int* __restrict__ tok, int a_comp,
    const __hip_bfloat16* __restrict__ As2, const __hip_bfloat16* __restrict__ BTs2,
    float* __restrict__ Cs2) {
  __shared__ __align__(16) bf16_t Asd[2][128 * 32];   // 2 x 8 KB
  __shared__ __align__(16) bf16_t Bsd[2][128 * 32];
  __shared__ int rowmap[128];
  int e = blockIdx.z;
  bool sh = (counts != nullptr) && (e == NE);
  int cnt = sh ? M : (counts ? counts[e] : M);
  int bm = blockIdx.y * 128;
  if (bm >= cnt) return;
  int bn = blockIdx.x * 128;
  int obase = sh ? 0 : (offsets ? offsets[e] : 0);
  const bf16_t* Ab = sh ? (const bf16_t*)As2 : (const bf16_t*)A;
  const bf16_t* BTe = sh ? (const bf16_t*)BTs2 : ((const bf16_t*)BT + (size_t)e * N * K);
  float* Cp = sh ? Cs2 : C;
  const int* toke = (!sh && tok) ? tok + e * S : nullptr;
  int acompe = sh ? 0 : a_comp;
  int tid = threadIdx.x;
  if (tid < 128) {
    int gp = bm + tid;
    int cp = gp < cnt ? gp : cnt - 1;
    rowmap[tid] = toke ? toke[cp] : (acompe ? obase + cp : cp);
  }
  __syncthreads();
  int wave = tid >> 6, lane = tid & 63;
  int quad = lane >> 4, l16 = lane & 15;
  int wm = wave >> 1, wn = wave & 1;
  int srow = tid >> 2, scol = (tid & 3) * 8;
  size_t aoff0 = (size_t)rowmap[srow] * K + scol;
  size_t aoff1 = (size_t)rowmap[64 + srow] * K + scol;
  size_t boff0 = (size_t)(bn + srow) * K + scol;
  size_t boff1 = (size_t)(bn + 64 + srow) * K + scol;
  f32x4 acc[4][4];
#pragma unroll
  for (int i = 0; i < 4; ++i)
#pragma unroll
    for (int j = 0; j < 4; ++j) acc[i][j] = (f32x4){0.f, 0.f, 0.f, 0.f};

  // prologue: stage k0=0 into buf 0
  {
    char* AsB = (char*)Asd[0] + wave * 1024;
    char* BsB = (char*)Bsd[0] + wave * 1024;
    gll16(Ab + aoff0, AsB);
    gll16(Ab + aoff1, AsB + 4096);
    gll16(BTe + boff0, BsB);
    gll16(BTe + boff1, BsB + 4096);
  }
  for (int k0 = 0; k0 < K; k0 += 32) {
    int cur = (k0 >> 5) & 1;
    __syncthreads();                         // buf[cur] staged; prev reads done
    if (k0 + 32 < K) {                       // prefetch next into buf[cur^1]
      char* AsB = (char*)Asd[cur ^ 1] + wave * 1024;
      char* BsB = (char*)Bsd[cur ^ 1] + wave * 1024;
      gll16(Ab + aoff0 + k0 + 32, AsB);
      gll16(Ab + aoff1 + k0 + 32, AsB + 4096);
      gll16(BTe + boff0 + k0 + 32, BsB);
      gll16(BTe + boff1 + k0 + 32, BsB + 4096);
    }
    I4B8 af[4], bfr[4];
#pragma unroll
    for (int i = 0; i < 4; ++i)
      af[i].i = *(const int4*)(Asd[cur] + (wm * 64 + i * 16 + l16) * 32 + quad * 8);
#pragma unroll
    for (int j = 0; j < 4; ++j)
      bfr[j].i = *(const int4*)(Bsd[cur] + (wn * 64 + j * 16 + l16) * 32 + quad * 8);
#pragma unroll
    for (int i = 0; i < 4; ++i)
#pragma unroll
      for (int j = 0; j < 4; ++j)
        acc[i][j] = __builtin_amdgcn_mfma_f32_16x16x32_bf16(af[i].v, bfr[j].v, acc[i][j], 0, 0, 0);
  }
#pragma unroll
  for (int i = 0; i < 4; ++i) {
#pragma unroll
    for (int r = 0; r < 4; ++r) {
      int trow = wm * 64 + i * 16 + quad * 4 + r;
      int gp = bm + trow;
      if (gp < cnt) {
        size_t rowb = (size_t)(obase + gp) * N;
#pragma unroll
        for (int j = 0; j < 4; ++j) {
          int col = bn + wn * 64 + j * 16 + l16;
          size_t idx = rowb + col;
          Cp[idx] = acc[i][j][r] + (Cadd ? Cadd[idx] : 0.f);
        }
      }
    }
  }
}

// ------------------------------------------- dense MFMA GEMM, 128x64 tile (fp32 out)
// For under-gridded dense GEMMs (qkv: 384 blocks, wo: 256 blocks vs 192/128 at BN=128).
__global__ __launch_bounds__(256) void mgemm_n64_kernel(
    const __hip_bfloat16* __restrict__ A, const __hip_bfloat16* __restrict__ BT,
    const float* __restrict__ Cadd, float* __restrict__ C,
    int M, int N, int K) {
  __shared__ __align__(16) bf16_t Asd[2][128 * 32];   // 2 x 8 KB
  __shared__ __align__(16) bf16_t Bsd[2][64 * 32];    // 2 x 4 KB
  int bm = blockIdx.y * 128;
  int bn = blockIdx.x * 64;
  int tid = threadIdx.x;
  int wave = tid >> 6, lane = tid & 63;
  int quad = lane >> 4, l16 = lane & 15;
  int wm = wave >> 1, wn = wave & 1;
  int srow = tid >> 2, scol = (tid & 3) * 8;
  size_t aoff0 = (size_t)(bm + srow) * K + scol;
  size_t aoff1 = (size_t)(bm + 64 + srow) * K + scol;
  size_t boff = (size_t)(bn + srow) * K + scol;
  const bf16_t* Ab = (const bf16_t*)A;
  const bf16_t* Bb = (const bf16_t*)BT;
  f32x4 acc[4][2];
#pragma unroll
  for (int i = 0; i < 4; ++i)
#pragma unroll
    for (int j = 0; j < 2; ++j) acc[i][j] = (f32x4){0.f, 0.f, 0.f, 0.f};
  {
    char* AsB = (char*)Asd[0] + wave * 1024;
    gll16(Ab + aoff0, AsB);
    gll16(Ab + aoff1, AsB + 4096);
    gll16(Bb + boff, (char*)Bsd[0] + wave * 1024);
  }
  for (int k0 = 0; k0 < K; k0 += 32) {
    int cur = (k0 >> 5) & 1;
    __syncthreads();
    if (k0 + 32 < K) {
      char* AsB = (char*)Asd[cur ^ 1] + wave * 1024;
      gll16(Ab + aoff0 + k0 + 32, AsB);
      gll16(Ab + aoff1 + k0 + 32, AsB + 4096);
      gll16(Bb + boff + k0 + 32, (char*)Bsd[cur ^ 1] + wave * 1024);
    }
    I4B8 af[4], bf[2];
#pragma unroll
    for (int i = 0; i < 4; ++i)
      af[i].i = *(const int4*)(Asd[cur] + (wm * 64 + i * 16 + l16) * 32 + quad * 8);
#pragma unroll
    for (int j = 0; j < 2; ++j)
      bf[j].i = *(const int4*)(Bsd[cur] + (wn * 32 + j * 16 + l16) * 32 + quad * 8);
#pragma unroll
    for (int i = 0; i < 4; ++i)
#pragma unroll
      for (int j = 0; j < 2; ++j)
        acc[i][j] = __builtin_amdgcn_mfma_f32_16x16x32_bf16(af[i].v, bf[j].v, acc[i][j], 0, 0, 0);
  }
#pragma unroll
  for (int i = 0; i < 4; ++i) {
#pragma unroll
    for (int r = 0; r < 4; ++r) {
      int gp = bm + wm * 64 + i * 16 + quad * 4 + r;
      size_t rowb = (size_t)gp * N;
#pragma unroll
      for (int j = 0; j < 2; ++j) {
        int col = bn + wn * 32 + j * 16 + l16;
        size_t idx = rowb + col;
        C[idx] = acc[i][j][r] + (Cadd ? Cadd[idx] : 0.f);
      }
    }
  }
}

// ------------------------------------------- dual-B MFMA GEMM + silu, 128x64 tile
// R11/R12-verified BN=64 version (local optimum).
__global__ __launch_bounds__(256) void mgemm_gu_kernel(
    const __hip_bfloat16* __restrict__ A, const __hip_bfloat16* __restrict__ BTg,
    const __hip_bfloat16* __restrict__ BTu, __hip_bfloat16* __restrict__ act,
    int M, int N, int K,
    const int* __restrict__ counts, const int* __restrict__ offsets,
    const int* __restrict__ tok,
    const __hip_bfloat16* __restrict__ BTgs, const __hip_bfloat16* __restrict__ BTus,
    __hip_bfloat16* __restrict__ acts) {
  __shared__ __align__(16) bf16_t Asd[2][128 * 32];   // 2 x 8 KB
  __shared__ __align__(16) bf16_t Bgd[2][64 * 32];    // 2 x 4 KB
  __shared__ __align__(16) bf16_t Bud[2][64 * 32];    // 2 x 4 KB
  __shared__ int rowmap[128];
  int e = blockIdx.z;
  bool sh = (counts != nullptr) && (e == NE);
  int cnt = sh ? M : (counts ? counts[e] : M);
  int bm = blockIdx.y * 128;
  if (bm >= cnt) return;
  int bn = blockIdx.x * 64;
  const bf16_t* Ab = (const bf16_t*)A;
  const bf16_t* Bg = sh ? (const bf16_t*)BTgs : ((const bf16_t*)BTg + (size_t)e * N * K);
  const bf16_t* Bu = sh ? (const bf16_t*)BTus : ((const bf16_t*)BTu + (size_t)e * N * K);
  bf16_t* outp = sh ? (bf16_t*)acts : (bf16_t*)act;
  int obase = sh ? 0 : (offsets ? offsets[e] : 0);
  const int* toke = (!sh && tok) ? tok + e * S : nullptr;
  int tid = threadIdx.x;
  if (tid < 128) {
    int gp = bm + tid;
    int cp = gp < cnt ? gp : cnt - 1;
    rowmap[tid] = toke ? toke[cp] : cp;
  }
  __syncthreads();
  int wave = tid >> 6, lane = tid & 63;
  int quad = lane >> 4, l16 = lane & 15;
  int wm = wave >> 1, wn = wave & 1;
  int srow = tid >> 2, scol = (tid & 3) * 8;
  size_t aoff0 = (size_t)rowmap[srow] * K + scol;
  size_t aoff1 = (size_t)rowmap[64 + srow] * K + scol;
  size_t boff = (size_t)(bn + srow) * K + scol;
  f32x4 accg[4][2], accu[4][2];
#pragma unroll
  for (int i = 0; i < 4; ++i)
#pragma unroll
    for (int j = 0; j < 2; ++j) {
      accg[i][j] = (f32x4){0.f, 0.f, 0.f, 0.f};
      accu[i][j] = (f32x4){0.f, 0.f, 0.f, 0.f};
    }
  // prologue
  {
    char* AsB = (char*)Asd[0] + wave * 1024;
    gll16(Ab + aoff0, AsB);
    gll16(Ab + aoff1, AsB + 4096);
    gll16(Bg + boff, (char*)Bgd[0] + wave * 1024);
    gll16(Bu + boff, (char*)Bud[0] + wave * 1024);
  }
  for (int k0 = 0; k0 < K; k0 += 32) {
    int cur = (k0 >> 5) & 1;
    __syncthreads();
    if (k0 + 32 < K) {
      char* AsB = (char*)Asd[cur ^ 1] + wave * 1024;
      gll16(Ab + aoff0 + k0 + 32, AsB);
      gll16(Ab + aoff1 + k0 + 32, AsB + 4096);
      gll16(Bg + boff + k0 + 32, (char*)Bgd[cur ^ 1] + wave * 1024);
      gll16(Bu + boff + k0 + 32, (char*)Bud[cur ^ 1] + wave * 1024);
    }
    I4B8 af[4], bg[2], bu[2];
#pragma unroll
    for (int i = 0; i < 4; ++i)
      af[i].i = *(const int4*)(Asd[cur] + (wm * 64 + i * 16 + l16) * 32 + quad * 8);
#pragma unroll
    for (int j = 0; j < 2; ++j) {
      bg[j].i = *(const int4*)(Bgd[cur] + (wn * 32 + j * 16 + l16) * 32 + quad * 8);
      bu[j].i = *(const int4*)(Bud[cur] + (wn * 32 + j * 16 + l16) * 32 + quad * 8);
    }
#pragma unroll
    for (int i = 0; i < 4; ++i)
#pragma unroll
      for (int j = 0; j < 2; ++j) {
        accg[i][j] = __builtin_amdgcn_mfma_f32_16x16x32_bf16(af[i].v, bg[j].v, accg[i][j], 0, 0, 0);
        accu[i][j] = __builtin_amdgcn_mfma_f32_16x16x32_bf16(af[i].v, bu[j].v, accu[i][j], 0, 0, 0);
      }
  }
#pragma unroll
  for (int i = 0; i < 4; ++i) {
#pragma unroll
    for (int r = 0; r < 4; ++r) {
      int trow = wm * 64 + i * 16 + quad * 4 + r;
      int gp = bm + trow;
      if (gp < cnt) {
        size_t rowb = (size_t)(obase + gp) * N;
#pragma unroll
        for (int j = 0; j < 2; ++j) {
          int col = bn + wn * 32 + j * 16 + l16;
          float g = accg[i][j][r], uu = accu[i][j][r];
          float sg = g / (1.f + __expf(-g));
          outp[rowb + col] = __float2bfloat16(sg * uu);
        }
      }
    }
  }
}

// --------------------------------------------- q/k head rmsnorm + RoPE + bf16 cast
// grid (S, 6): y<5 = q/k heads; y==5 = V transpose tiles (fp32 qkv -> bf16 vT[256][2048]).
__global__ void qkv_post_kernel(const float* __restrict__ qkv,
                                const float* __restrict__ qw, const float* __restrict__ kw,
                                const float* __restrict__ cosb, const float* __restrict__ sinb,
                                __hip_bfloat16* __restrict__ qout,
                                __hip_bfloat16* __restrict__ kout,
                                __hip_bfloat16* __restrict__ vT) {
  __shared__ float tile[32][33];
  if (blockIdx.y == 5) {                     // V transpose: 512 tiles
    int bx = blockIdx.x;
    if (bx < 512) {
      int t0 = (bx & 63) * 32;
      int c0 = (bx >> 6) * 32;
      int tx = threadIdx.x & 31, ty = threadIdx.x >> 5;
#pragma unroll
      for (int i = 0; i < 4; ++i)
        tile[ty + i * 8][tx] = qkv[(size_t)(t0 + ty + i * 8) * QKV_N + (NH + NKV) * HD + c0 + tx];
      __syncthreads();
#pragma unroll
      for (int i = 0; i < 4; ++i)
        vT[(size_t)(c0 + ty + i * 8) * S + t0 + tx] = __float2bfloat16(tile[tx][ty + i * 8]);
    }
    return;
  }
  int t = blockIdx.x;
  int u = blockIdx.y * 4 + (threadIdx.x >> 6);
  int lane = threadIdx.x & 63;
  bool isq = (u < NH);
  int h = isq ? u : (u - NH);
  size_t src = (size_t)t * QKV_N + (isq ? (h * HD) : (NH * HD + h * HD)) + lane;
  float xv = qkv[src];
  float ss = xv * xv;
#pragma unroll
  for (int off = 32; off; off >>= 1) ss += __shfl_xor(ss, off);
  float r = rsqrtf(ss * (1.f / 64.f) + EPS);
  float xn = xv * r * (isq ? qw[lane] : kw[lane]);
  float other = __shfl_xor(xn, 32);
  float rot = (lane < 32) ? -other : other;
  float res = xn * cosb[t * 64 + lane] + rot * sinb[t * 64 + lane];
  if (isq) qout[(size_t)t * (NH * HD) + h * HD + lane] = __float2bfloat16(res * 0.125f);
  else     kout[(size_t)t * (NKV * HD) + h * HD + lane] = __float2bfloat16(res);
}

// --------------------------------------------- MFMA flash attention v5
// GQA-merged + KV-split-4 (flash-decoding). Block = (16-row q-tile, kv head, chunk z).
// 4 waves = 4 q-heads sharing K/V. T14 async staging (regs loaded one tile ahead).
// l accumulated via ones-column MFMA (no sum shuffles). Partials merged by attn_merge.
__global__ __launch_bounds__(256) void attn_kernel(
    const __hip_bfloat16* __restrict__ qg, const __hip_bfloat16* __restrict__ kg,
    const __hip_bfloat16* __restrict__ vT,
    float* __restrict__ op0, float* __restrict__ op1,
    float* __restrict__ op2, float* __restrict__ op3,
    float* __restrict__ mpart, float* __restrict__ lpart) {
  int qt = (int)(gridDim.x - 1) - (int)blockIdx.x;   // heavy tiles first
  int kvh = blockIdx.y;
  int z = blockIdx.z;
  int tid = threadIdx.x;
  int wave = tid >> 6, lane = tid & 63;
  int quad = lane >> 4, l16 = lane & 15;
  int h = kvh * 4 + wave;

  float* opz = (z == 0) ? op0 : (z == 1) ? op1 : (z == 2) ? op2 : op3;
  float* mp = mpart + (size_t)z * S * NH;
  float* lp = lpart + (size_t)z * S * NH;

  int nb = (qt >> 1) + 1;            // valid 32-blocks of kv
  int nt = (nb + 1) >> 1;            // 64-wide tiles
  bool halfm = (nb & 1) != 0;        // last tile only 32 valid
  int lo = (nt * z) >> 2;
  int hi = (nt * (z + 1)) >> 2;

  if (lo >= hi) {                    // empty chunk: zero partials
    int row = qt * 16 + (tid >> 4);
    float* od = opz + (size_t)row * (NH * HD) + kvh * 256 + (tid & 15) * 16;
    int4 zz = {0, 0, 0, 0};
#pragma unroll
    for (int i = 0; i < 4; ++i) *(int4*)(od + i * 4) = zz;
    if (tid < 64) {
      int rr = qt * 16 + (tid >> 2), hh = kvh * 4 + (tid & 3);
      mp[(size_t)rr * NH + hh] = -1e30f;
      lp[(size_t)rr * NH + hh] = 0.f;
    }
    return;
  }

  __shared__ __align__(16) int KsI[64 * 36];         // K tile [64 k][64 d + pad]
  __shared__ __align__(16) int VTI[64 * 36];         // V^T tile [64 d][64 k + pad]
  __shared__ __align__(16) int PsI[4][16 * 36];      // per-wave P [16 q][64 k + pad]

  I4B8 qf[2];
#pragma unroll
  for (int ch = 0; ch < 2; ++ch)
    qf[ch].i = *(const int4*)((const abf16*)qg +
        (size_t)(qt * 16 + l16) * (NH * HD) + h * HD + ch * 32 + quad * 8);

  I4B8 ones;
  ones.i = (int4){0x3F803F80, 0x3F803F80, 0x3F803F80, 0x3F803F80};   // 8x bf16 1.0

  float m_r[4];
  f32x4 o[4], o4;
#pragma unroll
  for (int r = 0; r < 4; ++r) m_r[r] = -1e30f;
#pragma unroll
  for (int sub = 0; sub < 4; ++sub) o[sub] = (f32x4){0.f, 0.f, 0.f, 0.f};
  o4 = (f32x4){0.f, 0.f, 0.f, 0.f};

  int sp = tid >> 3, sc = tid & 7;   // staging: 32 rows x 8 octets (x2 halves)
  const abf16* kb = (const abf16*)kg;
  const abf16* vb = (const abf16*)vT;

  // T14 prologue: load first tile into regs
  int4 rk0 = *(const int4*)(kb + (size_t)(lo * 64 + sp) * (NKV * HD) + kvh * HD + sc * 8);
  int4 rk1 = *(const int4*)(kb + (size_t)(lo * 64 + 32 + sp) * (NKV * HD) + kvh * HD + sc * 8);
  int4 rv0 = *(const int4*)(vb + (size_t)(kvh * HD + sp) * S + lo * 64 + sc * 8);
  int4 rv1 = *(const int4*)(vb + (size_t)(kvh * HD + 32 + sp) * S + lo * 64 + sc * 8);

  for (int kc = lo; kc < hi; ++kc) {
    // ---- write staged regs to LDS (prev compute done via loop-bottom barrier)
    *(int4*)&KsI[sp * 36 + sc * 4] = rk0;
    *(int4*)&KsI[(sp + 32) * 36 + sc * 4] = rk1;
    *(int4*)&VTI[sp * 36 + sc * 4] = rv0;
    *(int4*)&VTI[(sp + 32) * 36 + sc * 4] = rv1;
    __syncthreads();

    // ---- issue next tile loads (latency hides under compute below)
    if (kc + 1 < hi) {
      rk0 = *(const int4*)(kb + (size_t)((kc + 1) * 64 + sp) * (NKV * HD) + kvh * HD + sc * 8);
      rk1 = *(const int4*)(kb + (size_t)((kc + 1) * 64 + 32 + sp) * (NKV * HD) + kvh * HD + sc * 8);
      rv0 = *(const int4*)(vb + (size_t)(kvh * HD + sp) * S + (kc + 1) * 64 + sc * 8);
      rv1 = *(const int4*)(vb + (size_t)(kvh * HD + 32 + sp) * S + (kc + 1) * 64 + sc * 8);
    }

    // ---- QK^T: 16 q-rows x 64 k
    f32x4 s[4];
#pragma unroll
    for (int sub = 0; sub < 4; ++sub) s[sub] = (f32x4){0.f, 0.f, 0.f, 0.f};
    __builtin_amdgcn_s_setprio(1);
#pragma unroll
    for (int sub = 0; sub < 4; ++sub)
#pragma unroll
      for (int ch = 0; ch < 2; ++ch) {
        I4B8 ku;
        ku.i = *(const int4*)&KsI[(sub * 16 + l16) * 36 + ch * 16 + quad * 4];
        s[sub] = __builtin_amdgcn_mfma_f32_16x16x32_bf16(qf[ch].v, ku.v, s[sub], 0, 0, 0);
      }
    __builtin_amdgcn_s_setprio(0);
    if (halfm && kc == nt - 1) {
#pragma unroll
      for (int r = 0; r < 4; ++r) { s[2][r] = -1e30f; s[3][r] = -1e30f; }
    }

    // ---- online softmax: max-reduce + exp; sums come from ones-MFMA
    abf16* pw = (abf16*)PsI[wave];
#pragma unroll
    for (int r = 0; r < 4; ++r) {
      float v = fmaxf(fmaxf(s[0][r], s[1][r]), fmaxf(s[2][r], s[3][r]));
#pragma unroll
      for (int off = 1; off < 16; off <<= 1) v = fmaxf(v, __shfl_xor(v, off));
      float mx = fmaxf(m_r[r], v);
      float al = __expf(m_r[r] - mx);
      m_r[r] = mx;
      float p0 = __expf(s[0][r] - mx);
      float p1 = __expf(s[1][r] - mx);
      float p2 = __expf(s[2][r] - mx);
      float p3 = __expf(s[3][r] - mx);
      int prow = quad * 4 + r;
      pw[prow * 72 + l16]      = (bf16_t)p0;
      pw[prow * 72 + 16 + l16] = (bf16_t)p1;
      pw[prow * 72 + 32 + l16] = (bf16_t)p2;
      pw[prow * 72 + 48 + l16] = (bf16_t)p3;
      o4[r] *= al;
#pragma unroll
      for (int sub = 0; sub < 4; ++sub) o[sub][r] *= al;
    }

    // ---- PV: P(16x64) x V(64x64) + ones-column for row sums
    I4B8 pu[2];
#pragma unroll
    for (int ch = 0; ch < 2; ++ch)
      pu[ch].i = *(const int4*)&PsI[wave][l16 * 36 + ch * 16 + quad * 4];
    __builtin_amdgcn_s_setprio(1);
#pragma unroll
    for (int sub = 0; sub < 4; ++sub)
#pragma unroll
      for (int ch = 0; ch < 2; ++ch) {
        I4B8 vf;
        vf.i = *(const int4*)&VTI[(sub * 16 + l16) * 36 + ch * 16 + quad * 4];
        o[sub] = __builtin_amdgcn_mfma_f32_16x16x32_bf16(pu[ch].v, vf.v, o[sub], 0, 0, 0);
      }
#pragma unroll
    for (int ch = 0; ch < 2; ++ch)
      o4 = __builtin_amdgcn_mfma_f32_16x16x32_bf16(pu[ch].v, ones.v, o4, 0, 0, 0);
    __builtin_amdgcn_s_setprio(0);
    __syncthreads();
  }

  // epilogue: write raw partials (normalize at merge)
#pragma unroll
  for (int r = 0; r < 4; ++r) {
    int row = qt * 16 + quad * 4 + r;
    float* od = opz + (size_t)row * (NH * HD) + h * HD;
#pragma unroll
    for (int sub = 0; sub < 4; ++sub)
      od[sub * 16 + l16] = o[sub][r];
    if (l16 == 0) {
      mp[(size_t)row * NH + h] = m_r[r];
      lp[(size_t)row * NH + h] = o4[r];
    }
  }
}

// --------------------------------------------- merge KV-split-4 partials
__global__ void attn_merge_kernel(const float* __restrict__ op0,
                                  const float* __restrict__ op1,
                                  const float* __restrict__ op2,
                                  const float* __restrict__ op3,
                                  const float* __restrict__ mpart,
                                  const float* __restrict__ lpart,
                                  __hip_bfloat16* __restrict__ attn) {
  int row = blockIdx.x;
  int tid = threadIdx.x;
#pragma unroll
  for (int i = 0; i < 4; ++i) {
    int c = tid + i * 256;
    int h = c >> 6;
    float m0 = mpart[(size_t)row * NH + h];
    float m1 = mpart[(size_t)(S + row) * NH + h];
    float m2 = mpart[(size_t)(2 * S + row) * NH + h];
    float m3 = mpart[(size_t)(3 * S + row) * NH + h];
    float l0 = lpart[(size_t)row * NH + h];
    float l1 = lpart[(size_t)(S + row) * NH + h];
    float l2 = lpart[(size_t)(2 * S + row) * NH + h];
    float l3 = lpart[(size_t)(3 * S + row) * NH + h];
    float M = fmaxf(fmaxf(m0, m1), fmaxf(m2, m3));
    float a0 = __expf(m0 - M), a1 = __expf(m1 - M);
    float a2 = __expf(m2 - M), a3 = __expf(m3 - M);
    float l = l0 * a0 + l1 * a1 + l2 * a2 + l3 * a3;
    size_t idx = (size_t)row * (NH * HD) + c;
    float v = (op0[idx] * a0 + op1[idx] * a1 + op2[idx] * a2 + op3[idx] * a3) / l;
    attn[idx] = __float2bfloat16(v);
  }
}

// ---------------------------------------------------------------- router phase B
// ONE block, 1024 threads. Ballot-aggregated LDS counters -> tok_list/topk_pos.
__global__ __launch_bounds__(1024) void router_place_kernel(
    const int* __restrict__ topk_e, int* __restrict__ counts, int* __restrict__ offsets,
    int* __restrict__ tok_list, int* __restrict__ topk_pos) {
  __shared__ int lcnt[NE];
  int tid = threadIdx.x;
  int lane = tid & 63;
  if (tid < NE) lcnt[tid] = 0;
  __syncthreads();
#pragma unroll
  for (int r = 0; r < 2; ++r) {
    int t = r * 1024 + tid;
#pragma unroll
    for (int s = 0; s < 2; ++s) {
      int e = topk_e[2 * t + s];
      int pos = 0;
#pragma unroll
      for (int x = 0; x < NE; ++x) {
        unsigned long long mask = __ballot(e == x);
        if (mask) {
          int leader = __ffsll((unsigned long long)mask) - 1;
          int cnt = __popcll(mask);
          int base = 0;
          if (lane == leader) base = atomicAdd(&lcnt[x], cnt);
          base = __shfl(base, leader);
          if (e == x)
            pos = base + __popcll(mask & ((1ull << lane) - 1ull));
        }
      }
      topk_pos[2 * t + s] = pos;
      tok_list[e * S + pos] = t;
    }
  }
  __syncthreads();
  if (tid == 0) {
    int acc = 0;
    for (int e = 0; e < NE; ++e) { offsets[e] = acc; counts[e] = lcnt[e]; acc += lcnt[e]; }
  }
}

// ---------------------------------------------------------------- final add
__global__ void final_kernel(const float* __restrict__ x, const float* __restrict__ sout,
                             const float* __restrict__ eo,
                             const int* __restrict__ topk_e, const int* __restrict__ topk_pos,
                             const float* __restrict__ topk_w, const int* __restrict__ offsets,
                             float* __restrict__ out) {
  int t = blockIdx.x;
  int tid = threadIdx.x;
  int e0 = topk_e[2 * t], e1 = topk_e[2 * t + 1];
  size_t r0 = (size_t)offsets[e0] + topk_pos[2 * t];
  size_t r1 = (size_t)offsets[e1] + topk_pos[2 * t + 1];
  float w0 = topk_w[2 * t], w1 = topk_w[2 * t + 1];
#pragma unroll
  for (int i = 0; i < 4; ++i) {
    int d = tid + i * 256;
    size_t idx = (size_t)t * D + d;
    out[idx] = x[idx] + sout[idx] + w0 * eo[r0 * D + d] + w1 * eo[r1 * D + d];
  }
}

extern "C" void kernel_launch(void* const* d_in, const int* in_sizes, int n_in,
                              void* d_out, int out_size, void* d_ws, size_t ws_size,
                              hipStream_t stream) {
  const float* hidden  = (const float*)d_in[0];
  const float* cosb    = (const float*)d_in[1];
  const float* sinb    = (const float*)d_in[2];
  const float* w_qkv   = (const float*)d_in[3];
  const float* w_o     = (const float*)d_in[4];
  const float* q_norm  = (const float*)d_in[5];
  const float* k_norm  = (const float*)d_in[6];
  const float* in_ln   = (const float*)d_in[7];
  const float* post_ln = (const float*)d_in[8];
  const float* router_w= (const float*)d_in[9];
  const float* w_gate  = (const float*)d_in[10];
  const float* w_up    = (const float*)d_in[11];
  const float* w_down  = (const float*)d_in[12];
  const float* ws_gate = (const float*)d_in[13];
  const float* ws_up   = (const float*)d_in[14];
  const float* ws_down = (const float*)d_in[15];
  float* out = (float*)d_out;
  float* ws = (float*)d_ws;

  typedef __hip_bfloat16 hbf;
  // weights (bf16)
  hbf* wqkvT = (hbf*)(ws);                      // 1.5M el
  hbf* woT   = (hbf*)(ws +  768 * 1024);        // 1M el
  hbf* wgT   = (hbf*)(ws + 1280 * 1024);        // 8M el
  hbf* wuT   = (hbf*)(ws + 5376 * 1024);        // 8M el
  hbf* wdT   = (hbf*)(ws + 9472 * 1024);        // 8M el
  hbf* wsgT  = (hbf*)(ws + 13568 * 1024);       // 1M el
  hbf* wsuT  = (hbf*)(ws + 14080 * 1024);       // 1M el
  hbf* wsdT  = (hbf*)(ws + 14592 * 1024);       // 1M el
  // activations
  hbf*   hb      = (hbf*)(ws + 15104 * 1024);   // [15104K,16128K) floats, dead after qkv GEMM
  float* qkv     = ws + 16128 * 1024;           // [16128K,19200K), dead after qkv_post
  hbf*   qbB     = (hbf*)(ws + 19200 * 1024);
  hbf*   kbB     = (hbf*)(ws + 20224 * 1024);
  hbf*   vTb     = (hbf*)(ws + 20480 * 1024);   // V^T [256][2048]
  hbf*   attnb16 = (hbf*)(ws + 20736 * 1024);
  float* x       = ws + 22784 * 1024;           // 2M fl (written by wo GEMM, after merge)
  hbf*   h2b     = (hbf*)(ws + 26880 * 1024);   // written after attention
  hbf*   act     = (hbf*)(ws + 16128 * 1024);   // 4096x1024 bf16, aliases dead qkv
  float* eo      = ws + 18176 * 1024;           // 4096x1024 fp32, aliases dead q/k/v
  hbf*   sact    = (hbf*)(ws + 27904 * 1024);   // 2048x1024 bf16 (written by gu)
  float* sout    = ws + 28928 * 1024;           // 2048x1024 fp32 (written by down GEMM)
  // attention partials (live only attn -> merge; all regions dead during attention):
  float* mpart   = ws + 15104 * 1024;           // [4][S][NH]  (aliases dead hb)
  float* lpart   = mpart + 4 * S * NH;
  float* opart0  = ws + 16128 * 1024;           // aliases dead qkv
  float* opart1  = ws + 22784 * 1024;           // aliases x (written later)
  float* opart2  = ws + 28928 * 1024;           // aliases sout (written later)
  float* opart3  = ws + 26880 * 1024;           // aliases h2b+sact (written later)
  int* counts   = (int*)(ws + 30976 * 1024);
  int* offsets  = counts + NE;
  int* tok_list = offsets + NE;
  int* topk_e   = tok_list + NE * S;
  int* topk_pos = topk_e + 2 * S;
  float* topk_w = (float*)(topk_pos + 2 * S);

  dim3 b256(256);
  // transposes (64x64 tiles, R12-verified) + pre-attention rmsnorm fused (z==29)
  transpose_all_kernel<<<dim3(24, 16, 30), b256, 0, stream>>>(
      w_qkv, w_o, w_gate, w_up, w_down, ws_gate, ws_up, ws_down,
      wqkvT, woT, wgT, wuT, wdT, wsgT, wsuT, wsdT,
      hidden, in_ln, hb);
  // attention block
  mgemm_n64_kernel<<<dim3(QKV_N/64, S/128), b256, 0, stream>>>(hb, wqkvT, nullptr, qkv,
      S, QKV_N, D);
  qkv_post_kernel<<<dim3(S, 6), b256, 0, stream>>>(qkv, q_norm, k_norm, cosb, sinb, qbB, kbB, vTb);
  attn_kernel<<<dim3(S/16, NKV, 4), b256, 0, stream>>>(qbB, kbB, vTb,
      opart0, opart1, opart2, opart3, mpart, lpart);
  attn_merge_kernel<<<S, b256, 0, stream>>>(opart0, opart1, opart2, opart3,
      mpart, lpart, attnb16);
  mgemm_n64_kernel<<<dim3(D/64, S/128), b256, 0, stream>>>(attnb16, woT, hidden, x,
      S, D, D);
  // MoE block (shared expert merged as z == NE)
  rmsnorm_router_kernel<<<S, b256, 0, stream>>>(x, post_ln, router_w, h2b, topk_e, topk_w);
  router_place_kernel<<<1, 1024, 0, stream>>>(topk_e, counts, offsets, tok_list, topk_pos);
  mgemm_gu_kernel<<<dim3(NI/64, S/128, NE + 1), b256, 0, stream>>>(h2b, wgT, wuT, act,
      S, NI, D, counts, offsets, tok_list, wsgT, wsuT, sact);
  mgemm_kernel<<<dim3(D/128, S/128, NE + 1), b256, 0, stream>>>(act, wdT, nullptr, eo,
      S, D, NI, counts, offsets, nullptr, 1, sact, wsdT, sout);
  final_kernel<<<S, b256, 0, stream>>>(x, sout, eo, topk_e, topk_pos, topk_w, offsets, out);
}